// Round 9
// baseline (2778.069 us; speedup 1.0000x reference)
//
#include <hip/hip_runtime.h>
#include <hip/hip_fp16.h>

#define TSTEPS 276
#define NBATCH 32768
#define KDIM   4416   // 276*16
#define NPAD   320    // Wfc rows padded to 4*80
#define NOUT   276
#define NTILE  138    // KDIM / 32 = TSTEPS / 2
#define BTILE_ELE (320 * 32)     // elements per k-tile of W2t (10240)
#define BROWS  32     // batch rows per block (R9: 64 -> 32)

typedef _Float16 half8 __attribute__((ext_vector_type(8)));
typedef float    f32x4 __attribute__((ext_vector_type(4)));

__device__ __forceinline__ float fast_sigmoid(float x) {
    float e = __builtin_amdgcn_exp2f(-1.4426950408889634f * x);
    return __builtin_amdgcn_rcpf(1.0f + e);
}
__device__ __forceinline__ float fast_tanh(float x) {
    float e = __builtin_amdgcn_exp2f(2.885390081777927f * x);
    return 1.0f - 2.0f * __builtin_amdgcn_rcpf(1.0f + e);
}

// broadcast h from lane (lane&0x18)|j within each 8-lane group (BitMode swizzle)
#define HSWZ(dst, hb, j) dst = __int_as_float(__builtin_amdgcn_ds_swizzle(hb, ((j) << 5) | 0x18))

// ---------------- Kernel 1: Wfc fp32 -> fp16, K-permutation + B-TILING ------
// (unchanged, validated) W2t[k/32][320][32] fp16 = MFMA-fragment-native B.
// Storage k-index equals LSTM iteration index: p = s*16 + dir*8 + j.
__global__ __launch_bounds__(256) void conv_kernel(const float* __restrict__ Wfc,
                                                   _Float16* __restrict__ W2t)
{
    int i = blockIdx.x * 256 + threadIdx.x;        // destination index
    if (i < NPAD * KDIM) {
        int nk = i / BTILE_ELE;                    // k-tile index
        int r  = i - nk * BTILE_ELE;
        int n  = r >> 5;                           // 0..319 output row
        int kc = r & 31;
        int p  = nk * 32 + kc;                     // logical k
        _Float16 v = (_Float16)0.0f;
        if (n < NOUT) {
            int s = p >> 4, rr = p & 15;
            int src = (rr < 8) ? p : ((TSTEPS - 1 - s) * 16 + rr);
            v = (_Float16)Wfc[n * KDIM + src];
        }
        W2t[i] = v;
    }
}

// ---------------- Kernel 2: FUSED bidirectional LSTM + FC GEMM --------------
// R9: R8 counters (VALUBusy 77.5%, Occ 45.9% ~= ONE 1024-thr block/CU) show
// the loss is barrier-lockstep with no co-resident block to fill the bubble.
// Fix: block = 32 rows x 512 threads (8 waves), grid = 1024 -> 4 blocks/CU
// (2048 thr). While one block's waves converge on its barrier, 24 other
// waves keep the VALU fed; smaller groups converge faster. Per-wave tile
// work unchanged: 1 ds_read_b128 + 5 MFMAs (wave grid 2M x 4N, 16x80 tile).
// __launch_bounds__(512,8) pins <=64 VGPR (the m69 cliff) for 32 waves/CU.
// LSTM math / swizzles / W2t layout byte-identical to R8.
__global__ __launch_bounds__(512, 8) void fused_kernel(
    const float* __restrict__ x,
    const float* __restrict__ Wih_f, const float* __restrict__ Whh_f,
    const float* __restrict__ bih_f, const float* __restrict__ bhh_f,
    const float* __restrict__ Wih_b, const float* __restrict__ Whh_b,
    const float* __restrict__ bih_b, const float* __restrict__ bhh_b,
    const _Float16* __restrict__ W2, const float* __restrict__ bfc,
    float* __restrict__ out)
{
    __shared__ _Float16 sl[2][BROWS][32];          // double-buffered H k-tile, 4KB

    const int tid = threadIdx.x;
    const int k   = tid & 7;                       // hidden unit 0..7
    const int dir = (tid >> 3) & 1;
    const int row = tid >> 4;                      // local batch row 0..31
    const int m0  = blockIdx.x * BROWS;

    const float* Wih = dir ? Wih_b : Wih_f;
    const float* Whh = dir ? Whh_b : Whh_f;
    const float* bih = dir ? bih_b : bih_f;
    const float* bhh = dir ? bhh_b : bhh_f;

    float Wk[4][8], Wi0[4], Wi1[4], bs[4];
    #pragma unroll
    for (int g = 0; g < 4; ++g) {
        int wr = g * 8 + k;                        // PyTorch gate order i,f,g,o
        #pragma unroll
        for (int j = 0; j < 8; ++j) Wk[g][j] = Whh[wr * 8 + j];
        Wi0[g] = Wih[wr * 2 + 0];
        Wi1[g] = Wih[wr * 2 + 1];
        bs[g]  = bih[wr] + bhh[wr];
    }
    #pragma unroll
    for (int g = 0; g < 4; ++g) {                  // pin weights in ArchVGPRs
        #pragma unroll
        for (int j = 0; j < 8; ++j) asm volatile("" : "+v"(Wk[g][j]));
        asm volatile("" : "+v"(Wi0[g]));
        asm volatile("" : "+v"(Wi1[g]));
        asm volatile("" : "+v"(bs[g]));
    }

    const float2* __restrict__ xrow = (const float2*)(x + (size_t)(m0 + row) * (TSTEPS * 2));

    // MFMA wave roles: 8 waves = 2(M) x 4(N); wave tile 16 rows x 80 cols
    const int lane = tid & 63;
    const int w    = tid >> 6;
    const int wm   = w >> 2;                       // 0..1
    const int wn   = w & 3;                        // 0..3
    const int l15  = lane & 15;
    const int l4   = lane >> 4;
    const int arow = wm * 16 + l15;                // A-frag source row in slice
    const int aoff = (l4 ^ (arow & 3)) << 3;       // swizzled element offset

    const char* pb[5];                             // B fragment base pointers
    #pragma unroll
    for (int ni = 0; ni < 5; ++ni)
        pb[ni] = (const char*)W2 + (wn * 80 + ni * 16 + l15) * 64 + l4 * 16;

    f32x4 acc[5] = {};

    // swizzled chunk element offsets for the two steps of a pair
    const int c0 = ((0 | dir) ^ (row & 3)) << 3;   // s even: chunk = dir
    const int c1 = ((2 | dir) ^ (row & 3)) << 3;   // s odd : chunk = 2|dir

    float h = 0.0f, c = 0.0f;
    float2 xq0 = xrow[dir ? (TSTEPS - 1) : 0];
    float2 xq1 = xrow[dir ? (TSTEPS - 2) : 1];

    #pragma unroll 1
    for (int t = 0; t < NTILE; ++t) {
        // B fragments for tile t (used after the barrier; ~full-tile lead)
        half8 b[5];
        #pragma unroll
        for (int ni = 0; ni < 5; ++ni)
            b[ni] = *(const half8*)(pb[ni] + (size_t)t * 20480);

        // x prefetch for pair t+1 (clamped; values unused at the tail)
        int s2 = 2 * t + 2; s2 = (s2 > TSTEPS - 1) ? (TSTEPS - 1) : s2;
        int s3 = 2 * t + 3; s3 = (s3 > TSTEPS - 1) ? (TSTEPS - 1) : s3;
        const float2 nx0 = xrow[dir ? (TSTEPS - 1 - s2) : s2];
        const float2 nx1 = xrow[dir ? (TSTEPS - 1 - s3) : s3];

        _Float16* srow = &sl[t & 1][row][0];

        // ---- LSTM step s = 2t ----
        {
            const int hb = __float_as_int(h);
            float hv[8];
            HSWZ(hv[0], hb, 0); HSWZ(hv[1], hb, 1); HSWZ(hv[2], hb, 2); HSWZ(hv[3], hb, 3);
            HSWZ(hv[4], hb, 4); HSWZ(hv[5], hb, 5); HSWZ(hv[6], hb, 6); HSWZ(hv[7], hb, 7);
            float a4[4];
            #pragma unroll
            for (int g = 0; g < 4; ++g) {
                float a = fmaf(xq0.x, Wi0[g], bs[g]);
                a = fmaf(xq0.y, Wi1[g], a);
                #pragma unroll
                for (int j = 0; j < 8; ++j) a = fmaf(Wk[g][j], hv[j], a);
                a4[g] = a;
            }
            const float ig = fast_sigmoid(a4[0]);
            const float fg = fast_sigmoid(a4[1]);
            const float gg = fast_tanh(a4[2]);
            const float og = fast_sigmoid(a4[3]);
            c = fmaf(fg, c, ig * gg);
            h = og * fast_tanh(c);
            srow[c0 + k] = (_Float16)h;
        }
        // ---- LSTM step s = 2t+1 ----
        {
            const int hb = __float_as_int(h);
            float hv[8];
            HSWZ(hv[0], hb, 0); HSWZ(hv[1], hb, 1); HSWZ(hv[2], hb, 2); HSWZ(hv[3], hb, 3);
            HSWZ(hv[4], hb, 4); HSWZ(hv[5], hb, 5); HSWZ(hv[6], hb, 6); HSWZ(hv[7], hb, 7);
            float a4[4];
            #pragma unroll
            for (int g = 0; g < 4; ++g) {
                float a = fmaf(xq1.x, Wi0[g], bs[g]);
                a = fmaf(xq1.y, Wi1[g], a);
                #pragma unroll
                for (int j = 0; j < 8; ++j) a = fmaf(Wk[g][j], hv[j], a);
                a4[g] = a;
            }
            const float ig = fast_sigmoid(a4[0]);
            const float fg = fast_sigmoid(a4[1]);
            const float gg = fast_tanh(a4[2]);
            const float og = fast_sigmoid(a4[3]);
            c = fmaf(fg, c, ig * gg);
            h = og * fast_tanh(c);
            srow[c1 + k] = (_Float16)h;
        }

        __syncthreads();                           // slice t complete (buf reuse at
                                                   // t+2 is fenced by barrier t+1)

        const half8 a = *(const half8*)(&sl[t & 1][arow][aoff]);
        #pragma unroll
        for (int ni = 0; ni < 5; ++ni)
            acc[ni] = __builtin_amdgcn_mfma_f32_16x16x32_f16(a, b[ni], acc[ni], 0, 0, 0);

        xq0 = nx0; xq1 = nx1;
    }

    // epilogue: C layout col = l15 (N), row = l4*4 + g (M within 16-row tile)
    #pragma unroll
    for (int ni = 0; ni < 5; ++ni) {
        const int n = wn * 80 + ni * 16 + l15;
        if (n < NOUT) {
            const float bv = bfc[n];
            #pragma unroll
            for (int g = 0; g < 4; ++g)
                out[(size_t)(m0 + wm * 16 + l4 * 4 + g) * NOUT + n] = acc[ni][g] + bv;
        }
    }
}

extern "C" void kernel_launch(void* const* d_in, const int* in_sizes, int n_in,
                              void* d_out, int out_size, void* d_ws, size_t ws_size,
                              hipStream_t stream) {
    const float* x     = (const float*)d_in[0];
    const float* Wih_f = (const float*)d_in[1];
    const float* Whh_f = (const float*)d_in[2];
    const float* bih_f = (const float*)d_in[3];
    const float* bhh_f = (const float*)d_in[4];
    const float* Wih_b = (const float*)d_in[5];
    const float* Whh_b = (const float*)d_in[6];
    const float* bih_b = (const float*)d_in[7];
    const float* bhh_b = (const float*)d_in[8];
    const float* Wfc   = (const float*)d_in[9];
    const float* bfc   = (const float*)d_in[10];
    float* out = (float*)d_out;

    _Float16* W2 = (_Float16*)d_ws;                // 2.76 MB, only workspace user

    conv_kernel<<<(NPAD * KDIM + 255) / 256, 256, 0, stream>>>(Wfc, W2);
    fused_kernel<<<NBATCH / BROWS, 512, 0, stream>>>(x, Wih_f, Whh_f, bih_f, bhh_f,
                                                     Wih_b, Whh_b, bih_b, bhh_b,
                                                     W2, bfc, out);
}

// Round 10
// 521.010 us; speedup vs baseline: 5.3321x; 5.3321x over previous
//
#include <hip/hip_runtime.h>
#include <hip/hip_fp16.h>

#define TSTEPS 276
#define NBATCH 32768
#define KDIM   4416   // 276*16
#define NPAD   320    // Wfc rows padded to 4*80
#define NOUT   276
#define NTILE  138    // KDIM / 32 = TSTEPS / 2
#define BTILE_ELE (320 * 32)     // elements per k-tile of W2t (10240)
#define BROWS  16     // batch rows per block (R10: 256-thread blocks)

typedef _Float16 half8 __attribute__((ext_vector_type(8)));
typedef float    f32x4 __attribute__((ext_vector_type(4)));

__device__ __forceinline__ float fast_sigmoid(float x) {
    float e = __builtin_amdgcn_exp2f(-1.4426950408889634f * x);
    return __builtin_amdgcn_rcpf(1.0f + e);
}
__device__ __forceinline__ float fast_tanh(float x) {
    float e = __builtin_amdgcn_exp2f(2.885390081777927f * x);
    return 1.0f - 2.0f * __builtin_amdgcn_rcpf(1.0f + e);
}

// broadcast h from lane (lane&0x18)|j within each 8-lane group (BitMode swizzle)
#define HSWZ(dst, hb, j) dst = __int_as_float(__builtin_amdgcn_ds_swizzle(hb, ((j) << 5) | 0x18))

// ---------------- Kernel 1: Wfc fp32 -> fp16, K-permutation + B-TILING ------
// (unchanged, validated) W2t[k/32][320][32] fp16 = MFMA-fragment-native B.
// Storage k-index equals LSTM iteration index: p = s*16 + dir*8 + j.
__global__ __launch_bounds__(256) void conv_kernel(const float* __restrict__ Wfc,
                                                   _Float16* __restrict__ W2t)
{
    int i = blockIdx.x * 256 + threadIdx.x;        // destination index
    if (i < NPAD * KDIM) {
        int nk = i / BTILE_ELE;                    // k-tile index
        int r  = i - nk * BTILE_ELE;
        int n  = r >> 5;                           // 0..319 output row
        int kc = r & 31;
        int p  = nk * 32 + kc;                     // logical k
        _Float16 v = (_Float16)0.0f;
        if (n < NOUT) {
            int s = p >> 4, rr = p & 15;
            int src = (rr < 8) ? p : ((TSTEPS - 1 - s) * 16 + rr);
            v = (_Float16)Wfc[n * KDIM + src];
        }
        W2t[i] = v;
    }
}

// ---------------- Kernel 2: FUSED bidirectional LSTM + FC GEMM --------------
// R10: R9's launch_bounds(512,8) capped unified regs at 64 -> compiler
// spilled weights/frags to scratch (VGPR_Count 32, FETCH 7.5GB, WRITE 3.5GB,
// VALUBusy 13%). REVERTED. The co-residency theory (R8: Occ 46% = one
// 1024-thr block/CU, barrier bubble unfillable) is attacked the safe way:
// SMALLER BLOCKS at full register budget. Block = 16 rows x 256 thr
// (4 waves), grid 2048, launch_bounds(256,4) (cap 128 -> no spill).
// At ~96 unified regs/wave, 4-5 blocks/CU co-reside; while one block sits
// at its barrier, 12-16 other waves keep the VALU fed. Wave grid 1Mx4N
// (tile 16x80): per-wave tile work identical to R8 (5 B-loads, 1 ds_read,
// 5 MFMAs). B L2 traffic doubles to 5.7GB -- acceptable: R8 proved B is
// L2/L3-served (FETCH = x only), 5.7GB/~400us ~= 14 TB/s < 34.5 L2 ceiling.
__global__ __launch_bounds__(256, 4) void fused_kernel(
    const float* __restrict__ x,
    const float* __restrict__ Wih_f, const float* __restrict__ Whh_f,
    const float* __restrict__ bih_f, const float* __restrict__ bhh_f,
    const float* __restrict__ Wih_b, const float* __restrict__ Whh_b,
    const float* __restrict__ bih_b, const float* __restrict__ bhh_b,
    const _Float16* __restrict__ W2, const float* __restrict__ bfc,
    float* __restrict__ out)
{
    __shared__ _Float16 sl[2][BROWS][32];          // double-buffered H k-tile, 2KB

    const int tid = threadIdx.x;
    const int k   = tid & 7;                       // hidden unit 0..7
    const int dir = (tid >> 3) & 1;
    const int row = tid >> 4;                      // local batch row 0..15
    const int m0  = blockIdx.x * BROWS;

    const float* Wih = dir ? Wih_b : Wih_f;
    const float* Whh = dir ? Whh_b : Whh_f;
    const float* bih = dir ? bih_b : bih_f;
    const float* bhh = dir ? bhh_b : bhh_f;

    float Wk[4][8], Wi0[4], Wi1[4], bs[4];
    #pragma unroll
    for (int g = 0; g < 4; ++g) {
        int wr = g * 8 + k;                        // PyTorch gate order i,f,g,o
        #pragma unroll
        for (int j = 0; j < 8; ++j) Wk[g][j] = Whh[wr * 8 + j];
        Wi0[g] = Wih[wr * 2 + 0];
        Wi1[g] = Wih[wr * 2 + 1];
        bs[g]  = bih[wr] + bhh[wr];
    }
    #pragma unroll
    for (int g = 0; g < 4; ++g) {                  // pin weights in ArchVGPRs
        #pragma unroll
        for (int j = 0; j < 8; ++j) asm volatile("" : "+v"(Wk[g][j]));
        asm volatile("" : "+v"(Wi0[g]));
        asm volatile("" : "+v"(Wi1[g]));
        asm volatile("" : "+v"(bs[g]));
    }

    const float2* __restrict__ xrow = (const float2*)(x + (size_t)(m0 + row) * (TSTEPS * 2));

    // MFMA wave roles: 4 waves = 1(M) x 4(N); wave tile 16 rows x 80 cols
    const int lane = tid & 63;
    const int w    = tid >> 6;
    const int wn   = w;                            // 0..3
    const int l15  = lane & 15;
    const int l4   = lane >> 4;
    const int arow = l15;                          // A-frag source row in slice
    const int aoff = (l4 ^ (arow & 3)) << 3;       // swizzled element offset

    const char* pb[5];                             // B fragment base pointers
    #pragma unroll
    for (int ni = 0; ni < 5; ++ni)
        pb[ni] = (const char*)W2 + (wn * 80 + ni * 16 + l15) * 64 + l4 * 16;

    f32x4 acc[5] = {};

    // swizzled chunk element offsets for the two steps of a pair
    const int c0 = ((0 | dir) ^ (row & 3)) << 3;   // s even: chunk = dir
    const int c1 = ((2 | dir) ^ (row & 3)) << 3;   // s odd : chunk = 2|dir

    float h = 0.0f, c = 0.0f;
    float2 xq0 = xrow[dir ? (TSTEPS - 1) : 0];
    float2 xq1 = xrow[dir ? (TSTEPS - 2) : 1];

    #pragma unroll 1
    for (int t = 0; t < NTILE; ++t) {
        // B fragments for tile t (used after the barrier; ~full-tile lead)
        half8 b[5];
        #pragma unroll
        for (int ni = 0; ni < 5; ++ni)
            b[ni] = *(const half8*)(pb[ni] + (size_t)t * 20480);

        // x prefetch for pair t+1 (clamped; values unused at the tail)
        int s2 = 2 * t + 2; s2 = (s2 > TSTEPS - 1) ? (TSTEPS - 1) : s2;
        int s3 = 2 * t + 3; s3 = (s3 > TSTEPS - 1) ? (TSTEPS - 1) : s3;
        const float2 nx0 = xrow[dir ? (TSTEPS - 1 - s2) : s2];
        const float2 nx1 = xrow[dir ? (TSTEPS - 1 - s3) : s3];

        _Float16* srow = &sl[t & 1][row][0];

        // ---- LSTM step s = 2t ----
        {
            const int hb = __float_as_int(h);
            float hv[8];
            HSWZ(hv[0], hb, 0); HSWZ(hv[1], hb, 1); HSWZ(hv[2], hb, 2); HSWZ(hv[3], hb, 3);
            HSWZ(hv[4], hb, 4); HSWZ(hv[5], hb, 5); HSWZ(hv[6], hb, 6); HSWZ(hv[7], hb, 7);
            float a4[4];
            #pragma unroll
            for (int g = 0; g < 4; ++g) {
                float a = fmaf(xq0.x, Wi0[g], bs[g]);
                a = fmaf(xq0.y, Wi1[g], a);
                #pragma unroll
                for (int j = 0; j < 8; ++j) a = fmaf(Wk[g][j], hv[j], a);
                a4[g] = a;
            }
            const float ig = fast_sigmoid(a4[0]);
            const float fg = fast_sigmoid(a4[1]);
            const float gg = fast_tanh(a4[2]);
            const float og = fast_sigmoid(a4[3]);
            c = fmaf(fg, c, ig * gg);
            h = og * fast_tanh(c);
            srow[c0 + k] = (_Float16)h;
        }
        // ---- LSTM step s = 2t+1 ----
        {
            const int hb = __float_as_int(h);
            float hv[8];
            HSWZ(hv[0], hb, 0); HSWZ(hv[1], hb, 1); HSWZ(hv[2], hb, 2); HSWZ(hv[3], hb, 3);
            HSWZ(hv[4], hb, 4); HSWZ(hv[5], hb, 5); HSWZ(hv[6], hb, 6); HSWZ(hv[7], hb, 7);
            float a4[4];
            #pragma unroll
            for (int g = 0; g < 4; ++g) {
                float a = fmaf(xq1.x, Wi0[g], bs[g]);
                a = fmaf(xq1.y, Wi1[g], a);
                #pragma unroll
                for (int j = 0; j < 8; ++j) a = fmaf(Wk[g][j], hv[j], a);
                a4[g] = a;
            }
            const float ig = fast_sigmoid(a4[0]);
            const float fg = fast_sigmoid(a4[1]);
            const float gg = fast_tanh(a4[2]);
            const float og = fast_sigmoid(a4[3]);
            c = fmaf(fg, c, ig * gg);
            h = og * fast_tanh(c);
            srow[c1 + k] = (_Float16)h;
        }

        __syncthreads();                           // slice t complete (buf reuse at
                                                   // t+2 is fenced by barrier t+1)

        const half8 a = *(const half8*)(&sl[t & 1][arow][aoff]);
        #pragma unroll
        for (int ni = 0; ni < 5; ++ni)
            acc[ni] = __builtin_amdgcn_mfma_f32_16x16x32_f16(a, b[ni], acc[ni], 0, 0, 0);

        xq0 = nx0; xq1 = nx1;
    }

    // epilogue: C layout col = l15 (N), row = l4*4 + g (M within 16-row tile)
    #pragma unroll
    for (int ni = 0; ni < 5; ++ni) {
        const int n = wn * 80 + ni * 16 + l15;
        if (n < NOUT) {
            const float bv = bfc[n];
            #pragma unroll
            for (int g = 0; g < 4; ++g)
                out[(size_t)(m0 + l4 * 4 + g) * NOUT + n] = acc[ni][g] + bv;
        }
    }
}

extern "C" void kernel_launch(void* const* d_in, const int* in_sizes, int n_in,
                              void* d_out, int out_size, void* d_ws, size_t ws_size,
                              hipStream_t stream) {
    const float* x     = (const float*)d_in[0];
    const float* Wih_f = (const float*)d_in[1];
    const float* Whh_f = (const float*)d_in[2];
    const float* bih_f = (const float*)d_in[3];
    const float* bhh_f = (const float*)d_in[4];
    const float* Wih_b = (const float*)d_in[5];
    const float* Whh_b = (const float*)d_in[6];
    const float* bih_b = (const float*)d_in[7];
    const float* bhh_b = (const float*)d_in[8];
    const float* Wfc   = (const float*)d_in[9];
    const float* bfc   = (const float*)d_in[10];
    float* out = (float*)d_out;

    _Float16* W2 = (_Float16*)d_ws;                // 2.76 MB, only workspace user

    conv_kernel<<<(NPAD * KDIM + 255) / 256, 256, 0, stream>>>(Wfc, W2);
    fused_kernel<<<NBATCH / BROWS, 256, 0, stream>>>(x, Wih_f, Whh_f, bih_f, bhh_f,
                                                     Wih_b, Whh_b, bih_b, bhh_b,
                                                     W2, bfc, out);
}